// Round 2
// baseline (123.927 us; speedup 1.0000x reference)
//
#include <hip/hip_runtime.h>

// Problem constants: B=256, T=256, H=768, S=130
#define BB 256
#define TT 256
#define HH 768
#define SS 130
#define SP 144   // S padded to 9 n-tiles of 16
#define KC 64    // K-chunk
#define AS 72    // A_lds row stride in ushorts (64 + 8 pad; 144 B, 16B-aligned)
#define BS 72    // B_lds row stride in ushorts

typedef __attribute__((ext_vector_type(8))) __bf16 bf16x8;
typedef __attribute__((ext_vector_type(4))) float f32x4;

__device__ __forceinline__ unsigned f2bf(float f) {
    unsigned x = __builtin_bit_cast(unsigned, f);
    x = (x + 0x7FFFu + ((x >> 16) & 1u)) >> 16;
    return x & 0xFFFFu;
}

// ---- K0: W [768][130] f32 -> wsT [144][768] bf16 (transposed; pad rows zero) ----
__global__ __launch_bounds__(256)
void conv_w_kernel(const float* __restrict__ W, unsigned short* __restrict__ wsT)
{
    int idx = blockIdx.x * 256 + threadIdx.x;       // over 144*768/2 pairs
    if (idx >= SP * HH / 2) return;
    int s  = idx / (HH / 2);
    int kp = idx % (HH / 2);
    unsigned u = 0;
    if (s < SS) {
        float x = W[(size_t)(2 * kp) * SS + s];
        float y = W[(size_t)(2 * kp + 1) * SS + s];
        u = f2bf(x) | (f2bf(y) << 16);
    }
    *(unsigned*)(wsT + (size_t)s * HH + 2 * kp) = u;
}

// ---- K1: logits^T = (hidden[:,1:] @ W + b) written as out[b][s][t] ----
__global__ __launch_bounds__(256, 4)
void gemm_kernel(const float* __restrict__ hidden,
                 const unsigned short* __restrict__ wsT,
                 const float* __restrict__ bias,
                 float* __restrict__ out)
{
    __shared__ __align__(16) unsigned short A_us[64 * AS];  //  9216 B
    __shared__ __align__(16) unsigned short B_us[SP * BS];  // 20736 B

    const int bid  = blockIdx.x;
    const int b    = bid >> 2;          // batch row
    const int tb   = (bid & 3) << 6;    // token block base (64 tokens)
    const int tid  = threadIdx.x;
    const int wv   = tid >> 6;          // 4 waves, 16 tokens each
    const int lane = tid & 63;

    const float* Arow = hidden + (size_t)b * (TT + 1) * HH + HH + (size_t)tb * HH;

    f32x4 acc[9];
    #pragma unroll
    for (int j = 0; j < 9; ++j) acc[j] = (f32x4){0.f, 0.f, 0.f, 0.f};

    const int quad = tid & 15;   // float4 index within 64-wide k chunk
    const int trow = tid >> 4;   // 0..15

    for (int k0 = 0; k0 < HH; k0 += KC) {
        // stage A: 64 tokens x 64 k, fp32 -> bf16
        #pragma unroll
        for (int r = 0; r < 4; ++r) {
            int t = trow + 16 * r;
            float4 v = *(const float4*)(Arow + (size_t)t * HH + k0 + quad * 4);
            unsigned lo = f2bf(v.x) | (f2bf(v.y) << 16);
            unsigned hi = f2bf(v.z) | (f2bf(v.w) << 16);
            *(uint2*)(A_us + t * AS + quad * 4) = make_uint2(lo, hi);
        }
        // stage B: 144 s-rows x 64 k, bf16 16B copies (1152 chunks)
        #pragma unroll
        for (int i = 0; i < 5; ++i) {
            int c = tid + i * 256;
            if (c < SP * 8) {
                int s = c >> 3, kq = c & 7;
                *(uint4*)(B_us + s * BS + kq * 8) =
                    *(const uint4*)(wsT + (size_t)s * HH + k0 + kq * 8);
            }
        }
        __syncthreads();

        #pragma unroll
        for (int kh = 0; kh < 2; ++kh) {
            const int kof = kh * 32 + (lane >> 4) * 8;
            bf16x8 af = *(const bf16x8*)(A_us + (wv * 16 + (lane & 15)) * AS + kof);
            #pragma unroll
            for (int nt = 0; nt < 9; ++nt) {
                bf16x8 bfr = *(const bf16x8*)(B_us + (nt * 16 + (lane & 15)) * BS + kof);
                acc[nt] = __builtin_amdgcn_mfma_f32_16x16x32_bf16(af, bfr, acc[nt], 0, 0, 0);
            }
        }
        __syncthreads();
    }

    // epilogue: +bias, transposed store out[b][s][t], t-contiguous float4 per lane
    const int trow_o = tb + wv * 16 + 4 * (lane >> 4);   // D row = (lane>>4)*4 + r
    #pragma unroll
    for (int nt = 0; nt < 9; ++nt) {
        int s = nt * 16 + (lane & 15);                    // D col = lane&15
        if (s < SS) {
            float bs = bias[s];
            float4 v = make_float4(acc[nt][0] + bs, acc[nt][1] + bs,
                                   acc[nt][2] + bs, acc[nt][3] + bs);
            *(float4*)(out + ((size_t)b * SS + s) * TT + trow_o) = v;
        }
    }
}

// ---- K2: in-place ragged segment-mean along t for each (b, s) ----
__global__ __launch_bounds__(256)
void merge_kernel(const int* __restrict__ seg, float* __restrict__ out)
{
    __shared__ float C[SS * TT];        // 133120 B
    __shared__ int segl[TT];
    __shared__ int startw[TT];
    __shared__ int cntw[TT];

    const int b   = blockIdx.x;
    const int tid = threadIdx.x;
    float* obase = out + (size_t)b * SS * TT;

    // stage full row of transposed logits into LDS (coalesced float4)
    for (int i = tid; i < SS * TT / 4; i += 256)
        *(float4*)(C + i * 4) = *(const float4*)(obase + i * 4);

    segl[tid] = seg[b * TT + tid];
    cntw[tid] = 0;
    __syncthreads();

    {   // run boundaries (seg is row-sorted -> segments are contiguous runs)
        int id = segl[tid];
        bool first = (tid == 0) || (segl[tid - 1] != id);
        if (first) {
            int e = tid;
            while (e + 1 < TT && segl[e + 1] == id) ++e;
            startw[id] = tid;
            cntw[id]   = e - tid + 1;
        }
    }
    __syncthreads();

    // thread = word w; loop s: coalesced in-place writes; empty words -> 0
    const int   w   = tid;
    const int   cn  = cntw[w];
    const int   st  = (cn > 0) ? startw[w] : 0;
    const float inv = (cn > 0) ? 1.f / (float)cn : 0.f;
    for (int s = 0; s < SS; ++s) {
        float a = 0.f;
        for (int k = 0; k < cn; ++k) a += C[s * TT + st + k];
        obase[s * TT + w] = a * inv;   // bias already folded into logits by K1
    }
}

extern "C" void kernel_launch(void* const* d_in, const int* in_sizes, int n_in,
                              void* d_out, int out_size, void* d_ws, size_t ws_size,
                              hipStream_t stream)
{
    const float* hidden = (const float*)d_in[0];  // [256, 257, 768] f32
    const float* W      = (const float*)d_in[1];  // [768, 130] f32
    const float* bias   = (const float*)d_in[2];  // [130] f32
    const int*   seg    = (const int*)d_in[3];    // [256, 256] i32 (row-sorted)
    float* out = (float*)d_out;                   // [256, 130, 256] f32
    unsigned short* wsT = (unsigned short*)d_ws;  // [144][768] bf16 = 221184 B

    (void)in_sizes; (void)n_in; (void)ws_size; (void)out_size;

    conv_w_kernel<<<dim3((SP * HH / 2 + 255) / 256), dim3(256), 0, stream>>>(W, wsT);
    gemm_kernel<<<dim3(BB * 4), dim3(256), 0, stream>>>(hidden, wsT, bias, out);
    merge_kernel<<<dim3(BB), dim3(256), 0, stream>>>(seg, out);
}

// Round 3
// 91.619 us; speedup vs baseline: 1.3526x; 1.3526x over previous
//
#include <hip/hip_runtime.h>

// Problem constants: B=256, T=256, H=768, S=130
#define BB 256
#define TT 256
#define HH 768
#define SS 130
#define SP 144   // S padded to 9 n-tiles of 16
#define KC 64    // K-chunk per step (2 MFMA k-halves of 32)
#define AS 72    // A_lds row stride in ushorts (64 + 8 pad = 144 B)
#define BS 72    // B_lds row stride in ushorts
#define CSTR 50  // C chunk row stride in floats ([256][50] = 51200 B, aliases staging)

typedef __attribute__((ext_vector_type(8))) __bf16 bf16x8;
typedef __attribute__((ext_vector_type(4))) float f32x4;

__device__ __forceinline__ unsigned f2bf(float f) {
    unsigned x = __builtin_bit_cast(unsigned, f);
    x = (x + 0x7FFFu + ((x >> 16) & 1u)) >> 16;
    return x & 0xFFFFu;
}

// ---- K0: W [768][130] f32 -> wsT [144][768] bf16 (transposed; pad rows zeroed) ----
__global__ __launch_bounds__(256)
void conv_w_kernel(const float* __restrict__ W, unsigned short* __restrict__ wsT)
{
    int idx = blockIdx.x * 256 + threadIdx.x;
    if (idx >= SP * HH / 2) return;
    int s  = idx / (HH / 2);
    int kp = idx % (HH / 2);
    unsigned u = 0;
    if (s < SS) {
        float x = W[(size_t)(2 * kp) * SS + s];
        float y = W[(size_t)(2 * kp + 1) * SS + s];
        u = f2bf(x) | (f2bf(y) << 16);
    }
    *(unsigned*)(wsT + (size_t)s * HH + 2 * kp) = u;
}

// ---- fused: GEMM (prefetched staging) + in-block ragged segment-mean ----
__global__ __launch_bounds__(512, 2)
void fused_kernel(const float* __restrict__ hidden,
                  const unsigned short* __restrict__ wsT,
                  const float* __restrict__ bias,
                  const int*   __restrict__ seg,
                  float* __restrict__ out)
{
    __shared__ __align__(16) char smem[36864 + 20736];  // A + B staging; C chunk aliases
    __shared__ int   segl[TT];
    __shared__ int   startw[TT];
    __shared__ int   cntw[TT];
    __shared__ float bias_l[SP];

    unsigned short* A_us = (unsigned short*)smem;             // [256][AS]
    unsigned short* B_us = (unsigned short*)(smem + 36864);   // [SP][BS]
    float* C = (float*)smem;                                  // [256][CSTR]

    const int b    = blockIdx.x;
    const int tid  = threadIdx.x;
    const int wv   = tid >> 6;
    const int lane = tid & 63;

    if (tid < TT) { segl[tid] = seg[b * TT + tid]; cntw[tid] = 0; }
    if (tid >= 256 && tid < 256 + SP) bias_l[tid - 256] = (tid - 256 < SS) ? bias[tid - 256] : 0.f;
    __syncthreads();
    if (tid < TT) {   // run boundaries (seg row-sorted -> contiguous runs)
        int id = segl[tid];
        if (tid == 0 || segl[tid - 1] != id) {
            int e = tid;
            while (e + 1 < TT && segl[e + 1] == id) ++e;
            startw[id] = tid;
            cntw[id]   = e - tid + 1;
        }
    }
    // (covered by the K-loop barriers before merge reads these)

    const float* Arow = hidden + (size_t)b * (TT + 1) * HH + HH;  // skip [CLS]

    const int quad = tid & 15;   // float4 index within 64-wide k chunk
    const int trow = tid >> 4;   // 0..31

    f32x4 acc[2][9];
    #pragma unroll
    for (int i = 0; i < 2; ++i)
        #pragma unroll
        for (int j = 0; j < 9; ++j) acc[i][j] = (f32x4){0.f, 0.f, 0.f, 0.f};

    float4 pa[8];   // A prefetch: 8 tokens' float4 per thread
    uint4  pb[3];   // B prefetch: up to 3 16B chunks per thread

    // prologue: loads for k0 = 0
    #pragma unroll
    for (int r = 0; r < 8; ++r)
        pa[r] = *(const float4*)(Arow + (size_t)(trow + 32 * r) * HH + quad * 4);
    #pragma unroll
    for (int i = 0; i < 3; ++i) {
        int c = tid + 512 * i;
        if (c < SP * 8) pb[i] = *(const uint4*)(wsT + (size_t)(c >> 3) * HH + (c & 7) * 8);
    }

    for (int k0 = 0; k0 < HH; k0 += KC) {
        // convert + stage from prefetch regs
        #pragma unroll
        for (int r = 0; r < 8; ++r) {
            int t = trow + 32 * r;
            unsigned lo = f2bf(pa[r].x) | (f2bf(pa[r].y) << 16);
            unsigned hi = f2bf(pa[r].z) | (f2bf(pa[r].w) << 16);
            *(uint2*)(A_us + t * AS + quad * 4) = make_uint2(lo, hi);
        }
        #pragma unroll
        for (int i = 0; i < 3; ++i) {
            int c = tid + 512 * i;
            if (c < SP * 8) *(uint4*)(B_us + (c >> 3) * BS + (c & 7) * 8) = pb[i];
        }
        __syncthreads();

        // issue next step's loads BEFORE the MFMA phase (latency hides under MFMA + next barrier)
        const int kn = k0 + KC;
        if (kn < HH) {
            #pragma unroll
            for (int r = 0; r < 8; ++r)
                pa[r] = *(const float4*)(Arow + (size_t)(trow + 32 * r) * HH + kn + quad * 4);
            #pragma unroll
            for (int i = 0; i < 3; ++i) {
                int c = tid + 512 * i;
                if (c < SP * 8) pb[i] = *(const uint4*)(wsT + (size_t)(c >> 3) * HH + kn + (c & 7) * 8);
            }
        }

        #pragma unroll
        for (int kh = 0; kh < 2; ++kh) {
            const int kof = kh * 32 + (lane >> 4) * 8;
            bf16x8 a0 = *(const bf16x8*)(A_us + (wv * 32 +      (lane & 15)) * AS + kof);
            bf16x8 a1 = *(const bf16x8*)(A_us + (wv * 32 + 16 + (lane & 15)) * AS + kof);
            #pragma unroll
            for (int nt = 0; nt < 9; ++nt) {
                bf16x8 bfr = *(const bf16x8*)(B_us + (nt * 16 + (lane & 15)) * BS + kof);
                acc[0][nt] = __builtin_amdgcn_mfma_f32_16x16x32_bf16(a0, bfr, acc[0][nt], 0, 0, 0);
                acc[1][nt] = __builtin_amdgcn_mfma_f32_16x16x32_bf16(a1, bfr, acc[1][nt], 0, 0, 0);
            }
        }
        __syncthreads();
    }

    // ---- merge: 3 s-chunks of 48 columns; acc -> LDS -> run-mean -> out[b][s][w] ----
    float* obase = out + (size_t)b * SS * TT;
    const int w  = tid & 255;       // word id
    const int sh = tid >> 8;        // s-parity (2-way parallel over s)
    const int   cn  = cntw[w];
    const int   st  = (cn > 0) ? startw[w] : 0;
    const float inv = (cn > 0) ? 1.f / (float)cn : 0.f;

    #pragma unroll
    for (int ch = 0; ch < 3; ++ch) {
        // dump this chunk's 48 s-columns from acc regs into C [256 t][CSTR]
        #pragma unroll
        for (int mt = 0; mt < 2; ++mt) {
            int tb = wv * 32 + mt * 16 + 4 * (lane >> 4);   // D row = (lane>>4)*4 + r
            #pragma unroll
            for (int j = 0; j < 3; ++j) {
                int col = j * 16 + (lane & 15);              // D col = lane&15
                #pragma unroll
                for (int r = 0; r < 4; ++r)
                    C[(tb + r) * CSTR + col] = acc[mt][3 * ch + j][r];
            }
        }
        __syncthreads();

        const int slo  = ch * 48;
        const int scnt = (slo + 48 <= SS) ? 48 : (SS - slo);   // 48, 48, 34
        for (int s = sh; s < scnt; s += 2) {
            float a = 0.f;
            for (int k = 0; k < cn; ++k) a += C[(st + k) * CSTR + s];
            float v = (cn > 0) ? a * inv + bias_l[slo + s] : 0.f;  // empty word -> 0 (no bias)
            obase[(size_t)(slo + s) * TT + w] = v;
        }
        __syncthreads();
    }
}

extern "C" void kernel_launch(void* const* d_in, const int* in_sizes, int n_in,
                              void* d_out, int out_size, void* d_ws, size_t ws_size,
                              hipStream_t stream)
{
    const float* hidden = (const float*)d_in[0];  // [256, 257, 768] f32
    const float* W      = (const float*)d_in[1];  // [768, 130] f32
    const float* bias   = (const float*)d_in[2];  // [130] f32
    const int*   seg    = (const int*)d_in[3];    // [256, 256] i32 (row-sorted)
    float* out = (float*)d_out;                   // [256, 130, 256] f32
    unsigned short* wsT = (unsigned short*)d_ws;  // [144][768] bf16 = 221184 B

    (void)in_sizes; (void)n_in; (void)ws_size; (void)out_size;

    conv_w_kernel<<<dim3((SP * HH / 2 + 255) / 256), dim3(256), 0, stream>>>(W, wsT);
    fused_kernel<<<dim3(BB), dim3(512), 0, stream>>>(hidden, wsT, bias, seg, out);
}